// Round 14
// baseline (159.033 us; speedup 1.0000x reference)
//
#include <hip/hip_runtime.h>

#define N_NODES 100000
#define N_EDGES 1600000
#define F_IN 22
#define H1 128
#define H2 256
#define C_OUT 4

// Edge record: 4 bytes. src in bits [31:15] (17 bits), weight quantized to
// 15 bits in [14:0]. w in [0,1) -> wq = round(w*32767); max err 1.5e-5.
#define W_SCALE 32767.0f
#define W_INV   (1.0f / 32767.0f)

// Two-level binned sort parameters
#define BSHIFT 9                  // 512 nodes per bucket
#define NBUCK 196                 // ceil(100000/512)
#define CHUNK 4096                // edges per binA block (LDS-staged)
#define NBLK_A 391                // ceil(1.6M/4096)
#define BCAP 12288                // bucket capacity (padded totals <= ~12.2K)
#define BSLACK 3584               // 512 nodes * 7 max pad per node
#define XB_BLOCKS 4297            // ceil(100000*11/256)

// ---------------------------------------------------------------------------
// binA_xb_k: FUSED. Blocks [0,NBLK_A): single-pass coarse bin — read edges
// once, stage {rec,dst} in LDS, histogram, bulk-reserve, scatter to bucket
// regions. Blocks [NBLK_A,...): xb compression (x -> packed bf16 pairs).
// ---------------------------------------------------------------------------
__global__ __launch_bounds__(256) void binA_xb_k(
    const int* __restrict__ esrc, const int* __restrict__ edst,
    const float* __restrict__ ew, int* __restrict__ bcnt,
    uint2* __restrict__ binned,
    const float* __restrict__ x, unsigned* __restrict__ xb)
{
    __shared__ uint2 l_rec[CHUNK];          // 32KB
    __shared__ int l_base[NBUCK];
    __shared__ int l_cnt[NBUCK];
    int t = threadIdx.x;
    int bid = blockIdx.x;

    if (bid >= NBLK_A) {
        // ---- xb branch: compress x to packed bf16 pairs (RNE)
        int i = (bid - NBLK_A) * 256 + t;
        if (i < N_NODES * 11) {
            int n = i / 11, p = i - n * 11;
            unsigned u0 = __float_as_uint(x[n * F_IN + 2 * p]);
            unsigned u1 = __float_as_uint(x[n * F_IN + 2 * p + 1]);
            u0 = (u0 + 0x7fffu + ((u0 >> 16) & 1u)) >> 16;
            u1 = (u1 + 0x7fffu + ((u1 >> 16) & 1u)) >> 16;
            xb[i] = u0 | (u1 << 16);
        }
        return;
    }

    // ---- binA branch: single pass over CHUNK edges
    int e0 = bid * CHUNK;
    int n = min(CHUNK, N_EDGES - e0);

    for (int i = t; i < NBUCK; i += 256) l_cnt[i] = 0;
    __syncthreads();
    for (int i = t; i < n; i += 256) {
        int e = e0 + i;
        int d = edst[e];
        int wq = (int)(ew[e] * W_SCALE + 0.5f);
        wq = wq > 32767 ? 32767 : wq;
        unsigned rec = ((unsigned)esrc[e] << 15) | (unsigned)wq;
        l_rec[i] = make_uint2(rec, (unsigned)d);
        atomicAdd(&l_cnt[d >> BSHIFT], 1);
    }
    __syncthreads();
    for (int i = t; i < NBUCK; i += 256) {
        int c = l_cnt[i];
        l_base[i] = c ? atomicAdd(&bcnt[i], c) : 0;
    }
    __syncthreads();
    for (int i = t; i < NBUCK; i += 256) l_cnt[i] = 0;
    __syncthreads();
    for (int i = t; i < n; i += 256) {
        uint2 r = l_rec[i];
        int d = (int)r.y;
        int b = d >> BSHIFT;
        int off = l_base[b] + atomicAdd(&l_cnt[b], 1);
        if (off < BCAP)
            binned[(size_t)b * BCAP + off] = make_uint2(r.x, (unsigned)(d & 511));
    }
}

// ---------------------------------------------------------------------------
// scanB_wf_k: FUSED 2-block kernel. Block 0: exclusive scan of per-bucket
// REGION sizes (bcnt + pad slack) -> bbase. Block 1: Wf = W2@Wm (128x4),
// bhead = b2@Wm + bm.
// ---------------------------------------------------------------------------
__global__ __launch_bounds__(512) void scanB_wf_k(
    const int* __restrict__ bcnt, int* __restrict__ bbase,
    const float* __restrict__ W2, const float* __restrict__ Wm,
    const float* __restrict__ b2, const float* __restrict__ bm,
    float* __restrict__ Wf, float* __restrict__ bhead)
{
    int t = threadIdx.x;
    if (blockIdx.x == 0) {
        __shared__ int sA[512], sB[512];
        int v = (t < NBUCK) ? (bcnt[t] + BSLACK) : 0;
        sA[t] = v; __syncthreads();
        int* src = sA; int* dst = sB;
        for (int off = 1; off < 512; off <<= 1) {
            dst[t] = src[t] + (t >= off ? src[t - off] : 0);
            __syncthreads();
            int* tmp = src; src = dst; dst = tmp;
        }
        if (t < NBUCK) bbase[t] = (t > 0) ? src[t - 1] : 0;
    } else {
        int k = t >> 2, c = t & 3;
        float acc = 0.f;
        for (int j = 0; j < H2; ++j)
            acc = fmaf(W2[k * H2 + j], Wm[j * C_OUT + c], acc);
        Wf[k * C_OUT + c] = acc;
        if (t < C_OUT) {
            float a = bm[t];
            for (int j = 0; j < H2; ++j)
                a = fmaf(b2[j], Wm[j * C_OUT + t], a);
            bhead[t] = a;
        }
    }
}

// ---------------------------------------------------------------------------
// binB_k: one block per bucket. Per-node histogram -> PADDED (multiple of 8)
// exclusive scan -> rowbeg/rowend -> LDS-scatter (zero-filled pad) ->
// coalesced write. Pad records are 0 (src=0, w=0): contribute exactly 0.
// ---------------------------------------------------------------------------
__global__ __launch_bounds__(512) void binB_k(
    const uint2* __restrict__ binned, const int* __restrict__ bcnt,
    const int* __restrict__ bbase, int* __restrict__ rowbeg,
    int* __restrict__ rowend, unsigned* __restrict__ rec_s)
{
    __shared__ int l_hist[512];
    __shared__ int sA[512], sB[512];
    __shared__ int l_cur[512];
    __shared__ unsigned l_out[BCAP];
    int b = blockIdx.x;
    int t = threadIdx.x;
    int node0 = b << BSHIFT;
    int base = bbase[b];
    int cnt = min(bcnt[b], BCAP);
    const uint2* reg = binned + (size_t)b * BCAP;

    l_hist[t] = 0;
    __syncthreads();
    for (int i = t; i < cnt; i += 512)
        atomicAdd(&l_hist[reg[i].y], 1);
    __syncthreads();
    int pc = (l_hist[t] + 7) & ~7;
    sA[t] = pc; __syncthreads();
    int* src = sA; int* dst = sB;
    for (int off = 1; off < 512; off <<= 1) {
        dst[t] = src[t] + (t >= off ? src[t - off] : 0);
        __syncthreads();
        int* tmp = src; src = dst; dst = tmp;
    }
    int excl = (t > 0) ? src[t - 1] : 0;
    int ptot = src[511];
    int node = node0 + t;
    if (node < N_NODES) {
        rowbeg[node] = base + excl;
        rowend[node] = base + excl + pc;
    }
    l_cur[t] = excl;
    __syncthreads();
    for (int i = t; i < ptot; i += 512) l_out[i] = 0;
    __syncthreads();
    for (int i = t; i < cnt; i += 512) {
        uint2 r = reg[i];
        int p = atomicAdd(&l_cur[r.y], 1);
        l_out[p] = r.x;
    }
    __syncthreads();
    for (int i = t; i < ptot; i += 512)
        rec_s[base + i] = l_out[i];
}

// ---------------------------------------------------------------------------
// layer1z_k: z[d] = relu( (sum_e w_e * x[src_e]) @ W1 + b1 ) @ Wf.
// W1 staged in LDS as scalars [k][j][lane] -> epilogue reads 4x ds_read_b32
// at bank==lane: conflict-free + cross-half broadcast (round-13's float4
// layout cost 2.4M conflict cycles). Wf (2KB) also in LDS.
// ---------------------------------------------------------------------------
__global__ __launch_bounds__(256) void layer1z_k(
    const unsigned* __restrict__ xb,
    const int* __restrict__ rowbeg,
    const int* __restrict__ rowend,
    const unsigned* __restrict__ rec,
    const float* __restrict__ W1,
    const float* __restrict__ b1,
    const float* __restrict__ Wf,
    float4* __restrict__ z)
{
    __shared__ float ws1f[F_IN * 128];  // 11KB: [k][j][lane] = W1[k][4*lane+j]
    __shared__ float4 wsf[H1];          // 2KB:  Wf row r -> 4 cols
    __shared__ float ys[8][24];
    int tid = threadIdx.x;
    int g = tid >> 5, lane = tid & 31;
    int d = blockIdx.x * 8 + g;
    int beg = rowbeg[d], end = rowend[d];   // end-beg is a multiple of 8

    // stage weights (transposed scalar layout; ordered vs use by the barrier)
    for (int i = tid; i < F_IN * 128; i += 256) {
        int k = i >> 7, r = i & 127, j = r >> 5, l = r & 31;
        ws1f[i] = W1[(k << 7) + (l << 2) + j];
    }
    if (tid < H1) wsf[tid] = ((const float4*)Wf)[tid];

    int l2 = lane < 22 ? lane : 21;         // lanes 22..31 duplicate lane 21
    int eslot = l2 >= 11;
    int pair = l2 - 11 * eslot;

    float aA0 = 0.f, aA1 = 0.f, aA2 = 0.f, aA3 = 0.f;
    float aB0 = 0.f, aB1 = 0.f, aB2 = 0.f, aB3 = 0.f;
    for (int j = beg; j < end; j += 8) {
        unsigned q0 = rec[j + 0 + eslot];
        unsigned q1 = rec[j + 2 + eslot];
        unsigned q2 = rec[j + 4 + eslot];
        unsigned q3 = rec[j + 6 + eslot];
        float w0 = (float)(q0 & 0x7fffu) * W_INV;
        float w1 = (float)(q1 & 0x7fffu) * W_INV;
        float w2 = (float)(q2 & 0x7fffu) * W_INV;
        float w3 = (float)(q3 & 0x7fffu) * W_INV;
        unsigned x0 = xb[(size_t)(q0 >> 15) * 11 + pair];
        unsigned x1 = xb[(size_t)(q1 >> 15) * 11 + pair];
        unsigned x2 = xb[(size_t)(q2 >> 15) * 11 + pair];
        unsigned x3 = xb[(size_t)(q3 >> 15) * 11 + pair];
        aA0 = fmaf(w0, __uint_as_float(x0 << 16), aA0);
        aB0 = fmaf(w0, __uint_as_float(x0 & 0xFFFF0000u), aB0);
        aA1 = fmaf(w1, __uint_as_float(x1 << 16), aA1);
        aB1 = fmaf(w1, __uint_as_float(x1 & 0xFFFF0000u), aB1);
        aA2 = fmaf(w2, __uint_as_float(x2 << 16), aA2);
        aB2 = fmaf(w2, __uint_as_float(x2 & 0xFFFF0000u), aB2);
        aA3 = fmaf(w3, __uint_as_float(x3 << 16), aA3);
        aB3 = fmaf(w3, __uint_as_float(x3 & 0xFFFF0000u), aB3);
    }
    float sA = (aA0 + aA1) + (aA2 + aA3);
    float sB = (aB0 + aB1) + (aB2 + aB3);
    // combine the two eslot halves: lane p (<11) += lane p+11
    float oA = __shfl(sA, 11 + pair, 32);
    float oB = __shfl(sB, 11 + pair, 32);
    if (lane < 11) {
        ys[g][2 * pair]     = sA + oA;
        ys[g][2 * pair + 1] = sB + oB;
    }
    __syncthreads();

    // dense 22->128 from LDS (conflict-free): lane -> h1 cols 4*lane..4*lane+3
    float4 a = ((const float4*)b1)[lane];
#pragma unroll
    for (int k = 0; k < F_IN; ++k) {
        float y = ys[g][k];
        a.x = fmaf(y, ws1f[k * 128 + lane], a.x);
        a.y = fmaf(y, ws1f[k * 128 + 32 + lane], a.y);
        a.z = fmaf(y, ws1f[k * 128 + 64 + lane], a.z);
        a.w = fmaf(y, ws1f[k * 128 + 96 + lane], a.w);
    }
    a.x = a.x > 0.f ? a.x : 0.f;
    a.y = a.y > 0.f ? a.y : 0.f;
    a.z = a.z > 0.f ? a.z : 0.f;
    a.w = a.w > 0.f ? a.w : 0.f;

    // fold with Wf (from LDS) and reduce
    float av[4] = {a.x, a.y, a.z, a.w};
    float pl[4] = {0.f, 0.f, 0.f, 0.f};
#pragma unroll
    for (int r = 0; r < 4; ++r) {
        float4 w = wsf[lane * 4 + r];
        pl[0] = fmaf(av[r], w.x, pl[0]);
        pl[1] = fmaf(av[r], w.y, pl[1]);
        pl[2] = fmaf(av[r], w.z, pl[2]);
        pl[3] = fmaf(av[r], w.w, pl[3]);
    }
#pragma unroll
    for (int mask = 16; mask >= 1; mask >>= 1) {
#pragma unroll
        for (int c = 0; c < 4; ++c)
            pl[c] += __shfl_xor(pl[c], mask, 64);
    }
    if (lane == 0)
        z[d] = make_float4(pl[0], pl[1], pl[2], pl[3]);
}

// ---------------------------------------------------------------------------
// agg4_k: out[d] = log_softmax( (sum_e w_e * z[src_e]) + bhead ).
// 8 lanes per node; rows padded to multiples of 8 -> no tail divergence.
// ---------------------------------------------------------------------------
__global__ __launch_bounds__(256) void agg4_k(
    const float4* __restrict__ z,
    const int* __restrict__ rowbeg,
    const int* __restrict__ rowend,
    const unsigned* __restrict__ rec,
    const float* __restrict__ bhead,
    float* __restrict__ out)
{
    int tid = threadIdx.x;
    int g = tid >> 3, sub = tid & 7;
    int d = blockIdx.x * 32 + g;
    int beg = rowbeg[d], end = rowend[d];

    float4 acc = {0.f, 0.f, 0.f, 0.f};
    for (int j = beg + sub; j < end; j += 8) {
        unsigned r = rec[j];
        float w = (float)(r & 0x7fffu) * W_INV;
        float4 v = z[r >> 15];
        acc.x = fmaf(w, v.x, acc.x);
        acc.y = fmaf(w, v.y, acc.y);
        acc.z = fmaf(w, v.z, acc.z);
        acc.w = fmaf(w, v.w, acc.w);
    }
#pragma unroll
    for (int mask = 4; mask >= 1; mask >>= 1) {
        acc.x += __shfl_xor(acc.x, mask, 64);
        acc.y += __shfl_xor(acc.y, mask, 64);
        acc.z += __shfl_xor(acc.z, mask, 64);
        acc.w += __shfl_xor(acc.w, mask, 64);
    }
    if (sub == 0) {
        float l0 = acc.x + bhead[0];
        float l1 = acc.y + bhead[1];
        float l2 = acc.z + bhead[2];
        float l3 = acc.w + bhead[3];
        float mx = fmaxf(fmaxf(l0, l1), fmaxf(l2, l3));
        float s = expf(l0 - mx) + expf(l1 - mx) + expf(l2 - mx) + expf(l3 - mx);
        float lg = mx + logf(s);
        ((float4*)out)[d] = make_float4(l0 - lg, l1 - lg, l2 - lg, l3 - lg);
    }
}

extern "C" void kernel_launch(void* const* d_in, const int* in_sizes, int n_in,
                              void* d_out, int out_size, void* d_ws, size_t ws_size,
                              hipStream_t stream) {
    const float* x    = (const float*)d_in[0];
    const int*   esrc = (const int*)d_in[1];
    const int*   edst = (const int*)d_in[2];
    const float* ew   = (const float*)d_in[3];
    const float* W1   = (const float*)d_in[4];
    const float* b1   = (const float*)d_in[5];
    const float* W2   = (const float*)d_in[6];
    const float* b2   = (const float*)d_in[7];
    const float* Wm   = (const float*)d_in[8];
    const float* bm   = (const float*)d_in[9];
    float* out = (float*)d_out;

    // workspace layout (~36 MB)
    char* ws = (char*)d_ws;
    float4*   z      = (float4*)ws;   ws += (size_t)N_NODES * 16;            // 1.6MB
    uint2*    binned = (uint2*)ws;    ws += (size_t)NBUCK * BCAP * 8;        // 19.3MB
    unsigned* rec_s  = (unsigned*)ws; ws += (size_t)(N_EDGES + NBUCK * BSLACK) * 4; // 9.2MB
    unsigned* xb     = (unsigned*)ws; ws += (size_t)N_NODES * 11 * 4;        // 4.4MB
    int*      rowbeg = (int*)ws;      ws += (size_t)N_NODES * 4;             // 0.4MB
    int*      rowend = (int*)ws;      ws += (size_t)N_NODES * 4;             // 0.4MB
    int*      bcnt   = (int*)ws;      ws += NBUCK * 4;
    int*      bbase  = (int*)ws;      ws += NBUCK * 4;
    float*    Wf     = (float*)ws;    ws += H1 * C_OUT * 4;
    float*    bhead  = (float*)ws;    ws += C_OUT * 4;

    // ---- coarse bin (single pass) + xb compression, fused
    hipMemsetAsync(bcnt, 0, NBUCK * 4, stream);
    binA_xb_k<<<NBLK_A + XB_BLOCKS, 256, 0, stream>>>(
        esrc, edst, ew, bcnt, binned, x, xb);

    // ---- bucket-base scan + head weight fold, fused (2 blocks)
    scanB_wf_k<<<2, 512, 0, stream>>>(bcnt, bbase, W2, Wm, b2, bm, Wf, bhead);

    // ---- fine sort (writes rowbeg/rowend + padded rec_s)
    binB_k<<<NBUCK, 512, 0, stream>>>(binned, bcnt, bbase, rowbeg, rowend, rec_s);

    // ---- layer 1 fused through z = h1@Wf; layer 2 + head
    layer1z_k<<<N_NODES / 8, 256, 0, stream>>>(xb, rowbeg, rowend, rec_s, W1, b1, Wf, z);
    agg4_k<<<N_NODES / 32, 256, 0, stream>>>(z, rowbeg, rowend, rec_s, bhead, out);
}

// Round 15
// 115.778 us; speedup vs baseline: 1.3736x; 1.3736x over previous
//
#include <hip/hip_runtime.h>

#define N_NODES 100000
#define N_EDGES 1600000
#define F_IN 22
#define H1 128
#define H2 256
#define C_OUT 4

// Edge record: 4 bytes. src in bits [31:15] (17 bits), weight quantized to
// 15 bits in [14:0]. w in [0,1) -> wq = round(w*32767); max err 1.5e-5.
#define W_SCALE 32767.0f
#define W_INV   (1.0f / 32767.0f)

// Two-level binned sort parameters
#define BSHIFT 9                  // 512 nodes per bucket
#define NBUCK 196                 // ceil(100000/512)
#define CHUNK 4096                // edges per binA block (LDS-staged)
#define NBLK_A 391                // ceil(1.6M/4096)
#define BCAP 12288                // bucket capacity (padded totals <= ~12.2K)
#define BSLACK 3584               // 512 nodes * 7 max pad per node
#define XB_BLOCKS 4297            // ceil(100000*11/256)

// ---------------------------------------------------------------------------
// binA_xb_k: FUSED. Blocks [0,NBLK_A): single-pass coarse bin — read edges
// once, stage {rec,dst} in LDS, histogram, bulk-reserve, scatter to bucket
// regions. Blocks [NBLK_A,...): xb compression (x -> packed bf16 pairs).
// ---------------------------------------------------------------------------
__global__ __launch_bounds__(256) void binA_xb_k(
    const int* __restrict__ esrc, const int* __restrict__ edst,
    const float* __restrict__ ew, int* __restrict__ bcnt,
    uint2* __restrict__ binned,
    const float* __restrict__ x, unsigned* __restrict__ xb)
{
    __shared__ uint2 l_rec[CHUNK];          // 32KB
    __shared__ int l_base[NBUCK];
    __shared__ int l_cnt[NBUCK];
    int t = threadIdx.x;
    int bid = blockIdx.x;

    if (bid >= NBLK_A) {
        // ---- xb branch: compress x to packed bf16 pairs (RNE)
        int i = (bid - NBLK_A) * 256 + t;
        if (i < N_NODES * 11) {
            int n = i / 11, p = i - n * 11;
            unsigned u0 = __float_as_uint(x[n * F_IN + 2 * p]);
            unsigned u1 = __float_as_uint(x[n * F_IN + 2 * p + 1]);
            u0 = (u0 + 0x7fffu + ((u0 >> 16) & 1u)) >> 16;
            u1 = (u1 + 0x7fffu + ((u1 >> 16) & 1u)) >> 16;
            xb[i] = u0 | (u1 << 16);
        }
        return;
    }

    // ---- binA branch: single pass over CHUNK edges
    int e0 = bid * CHUNK;
    int n = min(CHUNK, N_EDGES - e0);

    for (int i = t; i < NBUCK; i += 256) l_cnt[i] = 0;
    __syncthreads();
    for (int i = t; i < n; i += 256) {
        int e = e0 + i;
        int d = edst[e];
        int wq = (int)(ew[e] * W_SCALE + 0.5f);
        wq = wq > 32767 ? 32767 : wq;
        unsigned rec = ((unsigned)esrc[e] << 15) | (unsigned)wq;
        l_rec[i] = make_uint2(rec, (unsigned)d);
        atomicAdd(&l_cnt[d >> BSHIFT], 1);
    }
    __syncthreads();
    for (int i = t; i < NBUCK; i += 256) {
        int c = l_cnt[i];
        l_base[i] = c ? atomicAdd(&bcnt[i], c) : 0;
    }
    __syncthreads();
    for (int i = t; i < NBUCK; i += 256) l_cnt[i] = 0;
    __syncthreads();
    for (int i = t; i < n; i += 256) {
        uint2 r = l_rec[i];
        int d = (int)r.y;
        int b = d >> BSHIFT;
        int off = l_base[b] + atomicAdd(&l_cnt[b], 1);
        if (off < BCAP)
            binned[(size_t)b * BCAP + off] = make_uint2(r.x, (unsigned)(d & 511));
    }
}

// ---------------------------------------------------------------------------
// scanB_wf_k: FUSED 2-block kernel. Block 0: exclusive scan of per-bucket
// REGION sizes (bcnt + pad slack) -> bbase. Block 1: Wf = W2@Wm (128x4),
// bhead = b2@Wm + bm.
// ---------------------------------------------------------------------------
__global__ __launch_bounds__(512) void scanB_wf_k(
    const int* __restrict__ bcnt, int* __restrict__ bbase,
    const float* __restrict__ W2, const float* __restrict__ Wm,
    const float* __restrict__ b2, const float* __restrict__ bm,
    float* __restrict__ Wf, float* __restrict__ bhead)
{
    int t = threadIdx.x;
    if (blockIdx.x == 0) {
        __shared__ int sA[512], sB[512];
        int v = (t < NBUCK) ? (bcnt[t] + BSLACK) : 0;
        sA[t] = v; __syncthreads();
        int* src = sA; int* dst = sB;
        for (int off = 1; off < 512; off <<= 1) {
            dst[t] = src[t] + (t >= off ? src[t - off] : 0);
            __syncthreads();
            int* tmp = src; src = dst; dst = tmp;
        }
        if (t < NBUCK) bbase[t] = (t > 0) ? src[t - 1] : 0;
    } else {
        int k = t >> 2, c = t & 3;
        float acc = 0.f;
        for (int j = 0; j < H2; ++j)
            acc = fmaf(W2[k * H2 + j], Wm[j * C_OUT + c], acc);
        Wf[k * C_OUT + c] = acc;
        if (t < C_OUT) {
            float a = bm[t];
            for (int j = 0; j < H2; ++j)
                a = fmaf(b2[j], Wm[j * C_OUT + t], a);
            bhead[t] = a;
        }
    }
}

// ---------------------------------------------------------------------------
// binB_k: one block per bucket. Per-node histogram -> PADDED (multiple of 8)
// exclusive scan -> rowbeg/rowend -> LDS-scatter (zero-filled pad) ->
// coalesced write. Pad records are 0 (src=0, w=0): contribute exactly 0.
// ---------------------------------------------------------------------------
__global__ __launch_bounds__(512) void binB_k(
    const uint2* __restrict__ binned, const int* __restrict__ bcnt,
    const int* __restrict__ bbase, int* __restrict__ rowbeg,
    int* __restrict__ rowend, unsigned* __restrict__ rec_s)
{
    __shared__ int l_hist[512];
    __shared__ int sA[512], sB[512];
    __shared__ int l_cur[512];
    __shared__ unsigned l_out[BCAP];
    int b = blockIdx.x;
    int t = threadIdx.x;
    int node0 = b << BSHIFT;
    int base = bbase[b];
    int cnt = min(bcnt[b], BCAP);
    const uint2* reg = binned + (size_t)b * BCAP;

    l_hist[t] = 0;
    __syncthreads();
    for (int i = t; i < cnt; i += 512)
        atomicAdd(&l_hist[reg[i].y], 1);
    __syncthreads();
    int pc = (l_hist[t] + 7) & ~7;
    sA[t] = pc; __syncthreads();
    int* src = sA; int* dst = sB;
    for (int off = 1; off < 512; off <<= 1) {
        dst[t] = src[t] + (t >= off ? src[t - off] : 0);
        __syncthreads();
        int* tmp = src; src = dst; dst = tmp;
    }
    int excl = (t > 0) ? src[t - 1] : 0;
    int ptot = src[511];
    int node = node0 + t;
    if (node < N_NODES) {
        rowbeg[node] = base + excl;
        rowend[node] = base + excl + pc;
    }
    l_cur[t] = excl;
    __syncthreads();
    for (int i = t; i < ptot; i += 512) l_out[i] = 0;
    __syncthreads();
    for (int i = t; i < cnt; i += 512) {
        uint2 r = reg[i];
        int p = atomicAdd(&l_cur[r.y], 1);
        l_out[p] = r.x;
    }
    __syncthreads();
    for (int i = t; i < ptot; i += 512)
        rec_s[base + i] = l_out[i];
}

// ---------------------------------------------------------------------------
// layer1z_k: z[d] = relu( (sum_e w_e * x[src_e]) @ W1 + b1 ) @ Wf.
// ROUND-15: exact revert to the round-13 version (float4 LDS staging of W1
// and Wf; VGPR 32, ~70% occupancy, measured 51.2us). Round-14's transposed
// scalar staging doubled VGPR (64) -> occupancy 40% -> 93.9us, and did NOT
// move SQ_LDS_BANK_CONFLICT (conflict source is elsewhere; ~4us, ignored).
// ---------------------------------------------------------------------------
__global__ __launch_bounds__(256) void layer1z_k(
    const unsigned* __restrict__ xb,
    const int* __restrict__ rowbeg,
    const int* __restrict__ rowend,
    const unsigned* __restrict__ rec,
    const float* __restrict__ W1,
    const float* __restrict__ b1,
    const float* __restrict__ Wf,
    float4* __restrict__ z)
{
    __shared__ float4 ws1[F_IN * 32];   // 11KB: W1 row-quads [k][lane]
    __shared__ float4 wsf[H1];          // 2KB:  Wf row r -> 4 cols
    __shared__ float ys[8][24];
    int tid = threadIdx.x;
    int g = tid >> 5, lane = tid & 31;
    int d = blockIdx.x * 8 + g;
    int beg = rowbeg[d], end = rowend[d];   // end-beg is a multiple of 8

    // stage weights (reads ordered vs epilogue by the existing barrier)
    for (int i = tid; i < F_IN * 32; i += 256) ws1[i] = ((const float4*)W1)[i];
    if (tid < H1) wsf[tid] = ((const float4*)Wf)[tid];

    int l2 = lane < 22 ? lane : 21;         // lanes 22..31 duplicate lane 21
    int eslot = l2 >= 11;
    int pair = l2 - 11 * eslot;

    float aA0 = 0.f, aA1 = 0.f, aA2 = 0.f, aA3 = 0.f;
    float aB0 = 0.f, aB1 = 0.f, aB2 = 0.f, aB3 = 0.f;
    for (int j = beg; j < end; j += 8) {
        unsigned q0 = rec[j + 0 + eslot];
        unsigned q1 = rec[j + 2 + eslot];
        unsigned q2 = rec[j + 4 + eslot];
        unsigned q3 = rec[j + 6 + eslot];
        float w0 = (float)(q0 & 0x7fffu) * W_INV;
        float w1 = (float)(q1 & 0x7fffu) * W_INV;
        float w2 = (float)(q2 & 0x7fffu) * W_INV;
        float w3 = (float)(q3 & 0x7fffu) * W_INV;
        unsigned x0 = xb[(size_t)(q0 >> 15) * 11 + pair];
        unsigned x1 = xb[(size_t)(q1 >> 15) * 11 + pair];
        unsigned x2 = xb[(size_t)(q2 >> 15) * 11 + pair];
        unsigned x3 = xb[(size_t)(q3 >> 15) * 11 + pair];
        aA0 = fmaf(w0, __uint_as_float(x0 << 16), aA0);
        aB0 = fmaf(w0, __uint_as_float(x0 & 0xFFFF0000u), aB0);
        aA1 = fmaf(w1, __uint_as_float(x1 << 16), aA1);
        aB1 = fmaf(w1, __uint_as_float(x1 & 0xFFFF0000u), aB1);
        aA2 = fmaf(w2, __uint_as_float(x2 << 16), aA2);
        aB2 = fmaf(w2, __uint_as_float(x2 & 0xFFFF0000u), aB2);
        aA3 = fmaf(w3, __uint_as_float(x3 << 16), aA3);
        aB3 = fmaf(w3, __uint_as_float(x3 & 0xFFFF0000u), aB3);
    }
    float sA = (aA0 + aA1) + (aA2 + aA3);
    float sB = (aB0 + aB1) + (aB2 + aB3);
    // combine the two eslot halves: lane p (<11) += lane p+11
    float oA = __shfl(sA, 11 + pair, 32);
    float oB = __shfl(sB, 11 + pair, 32);
    if (lane < 11) {
        ys[g][2 * pair]     = sA + oA;
        ys[g][2 * pair + 1] = sB + oB;
    }
    __syncthreads();

    // dense 22->128 from LDS weights: lane computes h1 cols 4*lane..4*lane+3
    float4 a = ((const float4*)b1)[lane];
#pragma unroll
    for (int k = 0; k < F_IN; ++k) {
        float y = ys[g][k];
        float4 w = ws1[k * 32 + lane];
        a.x = fmaf(y, w.x, a.x);
        a.y = fmaf(y, w.y, a.y);
        a.z = fmaf(y, w.z, a.z);
        a.w = fmaf(y, w.w, a.w);
    }
    a.x = a.x > 0.f ? a.x : 0.f;
    a.y = a.y > 0.f ? a.y : 0.f;
    a.z = a.z > 0.f ? a.z : 0.f;
    a.w = a.w > 0.f ? a.w : 0.f;

    // fold with Wf (from LDS) and reduce
    float av[4] = {a.x, a.y, a.z, a.w};
    float pl[4] = {0.f, 0.f, 0.f, 0.f};
#pragma unroll
    for (int r = 0; r < 4; ++r) {
        float4 w = wsf[lane * 4 + r];
        pl[0] = fmaf(av[r], w.x, pl[0]);
        pl[1] = fmaf(av[r], w.y, pl[1]);
        pl[2] = fmaf(av[r], w.z, pl[2]);
        pl[3] = fmaf(av[r], w.w, pl[3]);
    }
#pragma unroll
    for (int mask = 16; mask >= 1; mask >>= 1) {
#pragma unroll
        for (int c = 0; c < 4; ++c)
            pl[c] += __shfl_xor(pl[c], mask, 64);
    }
    if (lane == 0)
        z[d] = make_float4(pl[0], pl[1], pl[2], pl[3]);
}

// ---------------------------------------------------------------------------
// agg4_k: out[d] = log_softmax( (sum_e w_e * z[src_e]) + bhead ).
// 8 lanes per node; rows padded to multiples of 8 -> no tail divergence.
// ---------------------------------------------------------------------------
__global__ __launch_bounds__(256) void agg4_k(
    const float4* __restrict__ z,
    const int* __restrict__ rowbeg,
    const int* __restrict__ rowend,
    const unsigned* __restrict__ rec,
    const float* __restrict__ bhead,
    float* __restrict__ out)
{
    int tid = threadIdx.x;
    int g = tid >> 3, sub = tid & 7;
    int d = blockIdx.x * 32 + g;
    int beg = rowbeg[d], end = rowend[d];

    float4 acc = {0.f, 0.f, 0.f, 0.f};
    for (int j = beg + sub; j < end; j += 8) {
        unsigned r = rec[j];
        float w = (float)(r & 0x7fffu) * W_INV;
        float4 v = z[r >> 15];
        acc.x = fmaf(w, v.x, acc.x);
        acc.y = fmaf(w, v.y, acc.y);
        acc.z = fmaf(w, v.z, acc.z);
        acc.w = fmaf(w, v.w, acc.w);
    }
#pragma unroll
    for (int mask = 4; mask >= 1; mask >>= 1) {
        acc.x += __shfl_xor(acc.x, mask, 64);
        acc.y += __shfl_xor(acc.y, mask, 64);
        acc.z += __shfl_xor(acc.z, mask, 64);
        acc.w += __shfl_xor(acc.w, mask, 64);
    }
    if (sub == 0) {
        float l0 = acc.x + bhead[0];
        float l1 = acc.y + bhead[1];
        float l2 = acc.z + bhead[2];
        float l3 = acc.w + bhead[3];
        float mx = fmaxf(fmaxf(l0, l1), fmaxf(l2, l3));
        float s = expf(l0 - mx) + expf(l1 - mx) + expf(l2 - mx) + expf(l3 - mx);
        float lg = mx + logf(s);
        ((float4*)out)[d] = make_float4(l0 - lg, l1 - lg, l2 - lg, l3 - lg);
    }
}

extern "C" void kernel_launch(void* const* d_in, const int* in_sizes, int n_in,
                              void* d_out, int out_size, void* d_ws, size_t ws_size,
                              hipStream_t stream) {
    const float* x    = (const float*)d_in[0];
    const int*   esrc = (const int*)d_in[1];
    const int*   edst = (const int*)d_in[2];
    const float* ew   = (const float*)d_in[3];
    const float* W1   = (const float*)d_in[4];
    const float* b1   = (const float*)d_in[5];
    const float* W2   = (const float*)d_in[6];
    const float* b2   = (const float*)d_in[7];
    const float* Wm   = (const float*)d_in[8];
    const float* bm   = (const float*)d_in[9];
    float* out = (float*)d_out;

    // workspace layout (~36 MB)
    char* ws = (char*)d_ws;
    float4*   z      = (float4*)ws;   ws += (size_t)N_NODES * 16;            // 1.6MB
    uint2*    binned = (uint2*)ws;    ws += (size_t)NBUCK * BCAP * 8;        // 19.3MB
    unsigned* rec_s  = (unsigned*)ws; ws += (size_t)(N_EDGES + NBUCK * BSLACK) * 4; // 9.2MB
    unsigned* xb     = (unsigned*)ws; ws += (size_t)N_NODES * 11 * 4;        // 4.4MB
    int*      rowbeg = (int*)ws;      ws += (size_t)N_NODES * 4;             // 0.4MB
    int*      rowend = (int*)ws;      ws += (size_t)N_NODES * 4;             // 0.4MB
    int*      bcnt   = (int*)ws;      ws += NBUCK * 4;
    int*      bbase  = (int*)ws;      ws += NBUCK * 4;
    float*    Wf     = (float*)ws;    ws += H1 * C_OUT * 4;
    float*    bhead  = (float*)ws;    ws += C_OUT * 4;

    // ---- coarse bin (single pass) + xb compression, fused
    hipMemsetAsync(bcnt, 0, NBUCK * 4, stream);
    binA_xb_k<<<NBLK_A + XB_BLOCKS, 256, 0, stream>>>(
        esrc, edst, ew, bcnt, binned, x, xb);

    // ---- bucket-base scan + head weight fold, fused (2 blocks)
    scanB_wf_k<<<2, 512, 0, stream>>>(bcnt, bbase, W2, Wm, b2, bm, Wf, bhead);

    // ---- fine sort (writes rowbeg/rowend + padded rec_s)
    binB_k<<<NBUCK, 512, 0, stream>>>(binned, bcnt, bbase, rowbeg, rowend, rec_s);

    // ---- layer 1 fused through z = h1@Wf; layer 2 + head
    layer1z_k<<<N_NODES / 8, 256, 0, stream>>>(xb, rowbeg, rowend, rec_s, W1, b1, Wf, z);
    agg4_k<<<N_NODES / 32, 256, 0, stream>>>(z, rowbeg, rowend, rec_s, bhead, out);
}

// Round 16
// 115.668 us; speedup vs baseline: 1.3749x; 1.0010x over previous
//
#include <hip/hip_runtime.h>

#define N_NODES 100000
#define N_EDGES 1600000
#define F_IN 22
#define H1 128
#define H2 256
#define C_OUT 4

// Edge record: 4 bytes. src in bits [31:15] (17 bits); bits [14:0] hold the
// bf16 bit-pattern of w (RNE). For w in [0,1], bf16 bits <= 0x3F80 < 2^15.
// Decode: w = uint_as_float((rec & 0x7fff) << 16). Rel err <= 2^-9.
#define WDEC(q) __uint_as_float(((q) & 0x7fffu) << 16)
#define BFLO(u) __uint_as_float((u) << 16)
#define BFHI(u) __uint_as_float((u) & 0xFFFF0000u)

// Two-level binned sort parameters
#define BSHIFT 9                  // 512 nodes per bucket
#define NBUCK 196                 // ceil(100000/512)
#define CHUNK 4096                // edges per binA block (LDS-staged)
#define NBLK_A 391                // ceil(1.6M/4096)
#define BCAP 12288                // bucket capacity (padded totals <= ~12.2K)
#define BSLACK 3584               // 512 nodes * 7 max pad per node
#define XB_BLOCKS 4297            // ceil(100000*11/256)

// ---------------------------------------------------------------------------
// binA_xb_k: FUSED. Blocks [0,NBLK_A): single-pass coarse bin — read edges
// once, stage {rec,dst} in LDS, histogram, bulk-reserve, scatter to bucket
// regions. Blocks [NBLK_A,...): xb compression (x -> packed bf16 pairs).
// ---------------------------------------------------------------------------
__global__ __launch_bounds__(256) void binA_xb_k(
    const int* __restrict__ esrc, const int* __restrict__ edst,
    const float* __restrict__ ew, int* __restrict__ bcnt,
    uint2* __restrict__ binned,
    const float* __restrict__ x, unsigned* __restrict__ xb)
{
    __shared__ uint2 l_rec[CHUNK];          // 32KB
    __shared__ int l_base[NBUCK];
    __shared__ int l_cnt[NBUCK];
    int t = threadIdx.x;
    int bid = blockIdx.x;

    if (bid >= NBLK_A) {
        // ---- xb branch: compress x to packed bf16 pairs (RNE)
        int i = (bid - NBLK_A) * 256 + t;
        if (i < N_NODES * 11) {
            int n = i / 11, p = i - n * 11;
            unsigned u0 = __float_as_uint(x[n * F_IN + 2 * p]);
            unsigned u1 = __float_as_uint(x[n * F_IN + 2 * p + 1]);
            u0 = (u0 + 0x7fffu + ((u0 >> 16) & 1u)) >> 16;
            u1 = (u1 + 0x7fffu + ((u1 >> 16) & 1u)) >> 16;
            xb[i] = u0 | (u1 << 16);
        }
        return;
    }

    // ---- binA branch: single pass over CHUNK edges
    int e0 = bid * CHUNK;
    int n = min(CHUNK, N_EDGES - e0);

    for (int i = t; i < NBUCK; i += 256) l_cnt[i] = 0;
    __syncthreads();
    for (int i = t; i < n; i += 256) {
        int e = e0 + i;
        int d = edst[e];
        // bf16 RNE encode of the weight into 15 bits
        unsigned u = __float_as_uint(ew[e]);
        unsigned bw = (u + 0x7fffu + ((u >> 16) & 1u)) >> 16;
        unsigned rec = ((unsigned)esrc[e] << 15) | bw;
        l_rec[i] = make_uint2(rec, (unsigned)d);
        atomicAdd(&l_cnt[d >> BSHIFT], 1);
    }
    __syncthreads();
    for (int i = t; i < NBUCK; i += 256) {
        int c = l_cnt[i];
        l_base[i] = c ? atomicAdd(&bcnt[i], c) : 0;
    }
    __syncthreads();
    for (int i = t; i < NBUCK; i += 256) l_cnt[i] = 0;
    __syncthreads();
    for (int i = t; i < n; i += 256) {
        uint2 r = l_rec[i];
        int d = (int)r.y;
        int b = d >> BSHIFT;
        int off = l_base[b] + atomicAdd(&l_cnt[b], 1);
        if (off < BCAP)
            binned[(size_t)b * BCAP + off] = make_uint2(r.x, (unsigned)(d & 511));
    }
}

// ---------------------------------------------------------------------------
// scanB_wf_k: FUSED 2-block kernel. Block 0: exclusive scan of per-bucket
// REGION sizes rounded to multiples of 8 (keeps every rowbeg 32B-aligned for
// the dwordx4 rec loads) -> bbase. Block 1: Wf = W2@Wm, bhead = b2@Wm + bm.
// ---------------------------------------------------------------------------
__global__ __launch_bounds__(512) void scanB_wf_k(
    const int* __restrict__ bcnt, int* __restrict__ bbase,
    const float* __restrict__ W2, const float* __restrict__ Wm,
    const float* __restrict__ b2, const float* __restrict__ bm,
    float* __restrict__ Wf, float* __restrict__ bhead)
{
    int t = threadIdx.x;
    if (blockIdx.x == 0) {
        __shared__ int sA[512], sB[512];
        int v = (t < NBUCK) ? ((bcnt[t] + BSLACK + 7) & ~7) : 0;
        sA[t] = v; __syncthreads();
        int* src = sA; int* dst = sB;
        for (int off = 1; off < 512; off <<= 1) {
            dst[t] = src[t] + (t >= off ? src[t - off] : 0);
            __syncthreads();
            int* tmp = src; src = dst; dst = tmp;
        }
        if (t < NBUCK) bbase[t] = (t > 0) ? src[t - 1] : 0;
    } else {
        int k = t >> 2, c = t & 3;
        float acc = 0.f;
        for (int j = 0; j < H2; ++j)
            acc = fmaf(W2[k * H2 + j], Wm[j * C_OUT + c], acc);
        Wf[k * C_OUT + c] = acc;
        if (t < C_OUT) {
            float a = bm[t];
            for (int j = 0; j < H2; ++j)
                a = fmaf(b2[j], Wm[j * C_OUT + t], a);
            bhead[t] = a;
        }
    }
}

// ---------------------------------------------------------------------------
// binB_k: one block per bucket. Per-node histogram -> PADDED (multiple of 8)
// exclusive scan -> rowbeg/rowend -> LDS-scatter (zero-filled pad) ->
// coalesced write. Pad records are 0 (src=0, w=0): contribute exactly 0.
// ---------------------------------------------------------------------------
__global__ __launch_bounds__(512) void binB_k(
    const uint2* __restrict__ binned, const int* __restrict__ bcnt,
    const int* __restrict__ bbase, int* __restrict__ rowbeg,
    int* __restrict__ rowend, unsigned* __restrict__ rec_s)
{
    __shared__ int l_hist[512];
    __shared__ int sA[512], sB[512];
    __shared__ int l_cur[512];
    __shared__ unsigned l_out[BCAP];
    int b = blockIdx.x;
    int t = threadIdx.x;
    int node0 = b << BSHIFT;
    int base = bbase[b];
    int cnt = min(bcnt[b], BCAP);
    const uint2* reg = binned + (size_t)b * BCAP;

    l_hist[t] = 0;
    __syncthreads();
    for (int i = t; i < cnt; i += 512)
        atomicAdd(&l_hist[reg[i].y], 1);
    __syncthreads();
    int pc = (l_hist[t] + 7) & ~7;
    sA[t] = pc; __syncthreads();
    int* src = sA; int* dst = sB;
    for (int off = 1; off < 512; off <<= 1) {
        dst[t] = src[t] + (t >= off ? src[t - off] : 0);
        __syncthreads();
        int* tmp = src; src = dst; dst = tmp;
    }
    int excl = (t > 0) ? src[t - 1] : 0;
    int ptot = src[511];
    int node = node0 + t;
    if (node < N_NODES) {
        rowbeg[node] = base + excl;
        rowend[node] = base + excl + pc;
    }
    l_cur[t] = excl;
    __syncthreads();
    for (int i = t; i < ptot; i += 512) l_out[i] = 0;
    __syncthreads();
    for (int i = t; i < cnt; i += 512) {
        uint2 r = reg[i];
        int p = atomicAdd(&l_cur[r.y], 1);
        l_out[p] = r.x;
    }
    __syncthreads();
    for (int i = t; i < ptot; i += 512)
        rec_s[base + i] = l_out[i];
}

// ---------------------------------------------------------------------------
// layer1z_k: z[d] = relu( (sum_e w_e * x[src_e]) @ W1 + b1 ) @ Wf.
// ROUND-16 edge loop: eslots own CONSECUTIVE edge quads -> rec loads fuse
// into dwordx4; 16-edge main body (8 xb gathers in flight per group, 2x the
// round-15 ILP) + single 8-edge tail; bf16 weight decode (and+shift).
// Accumulators reused (2 FMAs each) to keep VGPR under the 64 cliff.
// ---------------------------------------------------------------------------
__global__ __launch_bounds__(256) void layer1z_k(
    const unsigned* __restrict__ xb,
    const int* __restrict__ rowbeg,
    const int* __restrict__ rowend,
    const unsigned* __restrict__ rec,
    const float* __restrict__ W1,
    const float* __restrict__ b1,
    const float* __restrict__ Wf,
    float4* __restrict__ z)
{
    __shared__ float4 ws1[F_IN * 32];   // 11KB: W1 row-quads [k][lane]
    __shared__ float4 wsf[H1];          // 2KB:  Wf row r -> 4 cols
    __shared__ float ys[8][24];
    int tid = threadIdx.x;
    int g = tid >> 5, lane = tid & 31;
    int d = blockIdx.x * 8 + g;
    int beg = rowbeg[d], end = rowend[d];   // end-beg is a multiple of 8

    // stage weights (reads ordered vs epilogue by the existing barrier)
    for (int i = tid; i < F_IN * 32; i += 256) ws1[i] = ((const float4*)W1)[i];
    if (tid < H1) wsf[tid] = ((const float4*)Wf)[tid];

    int l2 = lane < 22 ? lane : 21;         // lanes 22..31 duplicate lane 21
    int eslot = l2 >= 11;
    int pair = l2 - 11 * eslot;

    float aA0 = 0.f, aA1 = 0.f, aA2 = 0.f, aA3 = 0.f;
    float aB0 = 0.f, aB1 = 0.f, aB2 = 0.f, aB3 = 0.f;
    int j = beg;
    // 16-edge main body: eslot e owns edges j+8e .. j+8e+7 (two dwordx4)
    for (; j + 16 <= end; j += 16) {
        const uint4* r4 = (const uint4*)(rec + j + 8 * eslot);
        uint4 qa = r4[0];
        uint4 qb = r4[1];
        unsigned x0 = xb[(size_t)(qa.x >> 15) * 11 + pair];
        unsigned x1 = xb[(size_t)(qa.y >> 15) * 11 + pair];
        unsigned x2 = xb[(size_t)(qa.z >> 15) * 11 + pair];
        unsigned x3 = xb[(size_t)(qa.w >> 15) * 11 + pair];
        unsigned x4 = xb[(size_t)(qb.x >> 15) * 11 + pair];
        unsigned x5 = xb[(size_t)(qb.y >> 15) * 11 + pair];
        unsigned x6 = xb[(size_t)(qb.z >> 15) * 11 + pair];
        unsigned x7 = xb[(size_t)(qb.w >> 15) * 11 + pair];
        float w0 = WDEC(qa.x), w1 = WDEC(qa.y), w2 = WDEC(qa.z), w3 = WDEC(qa.w);
        float w4 = WDEC(qb.x), w5 = WDEC(qb.y), w6 = WDEC(qb.z), w7 = WDEC(qb.w);
        aA0 = fmaf(w0, BFLO(x0), aA0); aB0 = fmaf(w0, BFHI(x0), aB0);
        aA1 = fmaf(w1, BFLO(x1), aA1); aB1 = fmaf(w1, BFHI(x1), aB1);
        aA2 = fmaf(w2, BFLO(x2), aA2); aB2 = fmaf(w2, BFHI(x2), aB2);
        aA3 = fmaf(w3, BFLO(x3), aA3); aB3 = fmaf(w3, BFHI(x3), aB3);
        aA0 = fmaf(w4, BFLO(x4), aA0); aB0 = fmaf(w4, BFHI(x4), aB0);
        aA1 = fmaf(w5, BFLO(x5), aA1); aB1 = fmaf(w5, BFHI(x5), aB1);
        aA2 = fmaf(w6, BFLO(x6), aA2); aB2 = fmaf(w6, BFHI(x6), aB2);
        aA3 = fmaf(w7, BFLO(x7), aA3); aB3 = fmaf(w7, BFHI(x7), aB3);
    }
    if (j < end) {
        // single 8-edge tail: eslot e owns edges j+4e .. j+4e+3 (one dwordx4)
        const uint4* r4 = (const uint4*)(rec + j + 4 * eslot);
        uint4 q = r4[0];
        unsigned x0 = xb[(size_t)(q.x >> 15) * 11 + pair];
        unsigned x1 = xb[(size_t)(q.y >> 15) * 11 + pair];
        unsigned x2 = xb[(size_t)(q.z >> 15) * 11 + pair];
        unsigned x3 = xb[(size_t)(q.w >> 15) * 11 + pair];
        float w0 = WDEC(q.x), w1 = WDEC(q.y), w2 = WDEC(q.z), w3 = WDEC(q.w);
        aA0 = fmaf(w0, BFLO(x0), aA0); aB0 = fmaf(w0, BFHI(x0), aB0);
        aA1 = fmaf(w1, BFLO(x1), aA1); aB1 = fmaf(w1, BFHI(x1), aB1);
        aA2 = fmaf(w2, BFLO(x2), aA2); aB2 = fmaf(w2, BFHI(x2), aB2);
        aA3 = fmaf(w3, BFLO(x3), aA3); aB3 = fmaf(w3, BFHI(x3), aB3);
    }
    float sA = (aA0 + aA1) + (aA2 + aA3);
    float sB = (aB0 + aB1) + (aB2 + aB3);
    // combine the two eslot halves: lane p (<11) += lane p+11
    float oA = __shfl(sA, 11 + pair, 32);
    float oB = __shfl(sB, 11 + pair, 32);
    if (lane < 11) {
        ys[g][2 * pair]     = sA + oA;
        ys[g][2 * pair + 1] = sB + oB;
    }
    __syncthreads();

    // dense 22->128 from LDS weights: lane computes h1 cols 4*lane..4*lane+3
    float4 a = ((const float4*)b1)[lane];
#pragma unroll
    for (int k = 0; k < F_IN; ++k) {
        float y = ys[g][k];
        float4 w = ws1[k * 32 + lane];
        a.x = fmaf(y, w.x, a.x);
        a.y = fmaf(y, w.y, a.y);
        a.z = fmaf(y, w.z, a.z);
        a.w = fmaf(y, w.w, a.w);
    }
    a.x = a.x > 0.f ? a.x : 0.f;
    a.y = a.y > 0.f ? a.y : 0.f;
    a.z = a.z > 0.f ? a.z : 0.f;
    a.w = a.w > 0.f ? a.w : 0.f;

    // fold with Wf (from LDS) and reduce
    float av[4] = {a.x, a.y, a.z, a.w};
    float pl[4] = {0.f, 0.f, 0.f, 0.f};
#pragma unroll
    for (int r = 0; r < 4; ++r) {
        float4 w = wsf[lane * 4 + r];
        pl[0] = fmaf(av[r], w.x, pl[0]);
        pl[1] = fmaf(av[r], w.y, pl[1]);
        pl[2] = fmaf(av[r], w.z, pl[2]);
        pl[3] = fmaf(av[r], w.w, pl[3]);
    }
#pragma unroll
    for (int mask = 16; mask >= 1; mask >>= 1) {
#pragma unroll
        for (int c = 0; c < 4; ++c)
            pl[c] += __shfl_xor(pl[c], mask, 64);
    }
    if (lane == 0)
        z[d] = make_float4(pl[0], pl[1], pl[2], pl[3]);
}

// ---------------------------------------------------------------------------
// agg4_k: out[d] = log_softmax( (sum_e w_e * z[src_e]) + bhead ).
// 8 lanes per node; rows padded to multiples of 8 -> no tail divergence.
// bf16 weight decode.
// ---------------------------------------------------------------------------
__global__ __launch_bounds__(256) void agg4_k(
    const float4* __restrict__ z,
    const int* __restrict__ rowbeg,
    const int* __restrict__ rowend,
    const unsigned* __restrict__ rec,
    const float* __restrict__ bhead,
    float* __restrict__ out)
{
    int tid = threadIdx.x;
    int g = tid >> 3, sub = tid & 7;
    int d = blockIdx.x * 32 + g;
    int beg = rowbeg[d], end = rowend[d];

    float4 acc = {0.f, 0.f, 0.f, 0.f};
    for (int j = beg + sub; j < end; j += 8) {
        unsigned r = rec[j];
        float w = WDEC(r);
        float4 v = z[r >> 15];
        acc.x = fmaf(w, v.x, acc.x);
        acc.y = fmaf(w, v.y, acc.y);
        acc.z = fmaf(w, v.z, acc.z);
        acc.w = fmaf(w, v.w, acc.w);
    }
#pragma unroll
    for (int mask = 4; mask >= 1; mask >>= 1) {
        acc.x += __shfl_xor(acc.x, mask, 64);
        acc.y += __shfl_xor(acc.y, mask, 64);
        acc.z += __shfl_xor(acc.z, mask, 64);
        acc.w += __shfl_xor(acc.w, mask, 64);
    }
    if (sub == 0) {
        float l0 = acc.x + bhead[0];
        float l1 = acc.y + bhead[1];
        float l2 = acc.z + bhead[2];
        float l3 = acc.w + bhead[3];
        float mx = fmaxf(fmaxf(l0, l1), fmaxf(l2, l3));
        float s = expf(l0 - mx) + expf(l1 - mx) + expf(l2 - mx) + expf(l3 - mx);
        float lg = mx + logf(s);
        ((float4*)out)[d] = make_float4(l0 - lg, l1 - lg, l2 - lg, l3 - lg);
    }
}

extern "C" void kernel_launch(void* const* d_in, const int* in_sizes, int n_in,
                              void* d_out, int out_size, void* d_ws, size_t ws_size,
                              hipStream_t stream) {
    const float* x    = (const float*)d_in[0];
    const int*   esrc = (const int*)d_in[1];
    const int*   edst = (const int*)d_in[2];
    const float* ew   = (const float*)d_in[3];
    const float* W1   = (const float*)d_in[4];
    const float* b1   = (const float*)d_in[5];
    const float* W2   = (const float*)d_in[6];
    const float* b2   = (const float*)d_in[7];
    const float* Wm   = (const float*)d_in[8];
    const float* bm   = (const float*)d_in[9];
    float* out = (float*)d_out;

    // workspace layout (~36 MB); rec_s 16B-aligned (offset divisible by 16)
    char* ws = (char*)d_ws;
    float4*   z      = (float4*)ws;   ws += (size_t)N_NODES * 16;            // 1.6MB
    uint2*    binned = (uint2*)ws;    ws += (size_t)NBUCK * BCAP * 8;        // 19.3MB
    unsigned* rec_s  = (unsigned*)ws; ws += (size_t)(N_EDGES + NBUCK * (BSLACK + 8)) * 4;
    unsigned* xb     = (unsigned*)ws; ws += (size_t)N_NODES * 11 * 4;        // 4.4MB
    int*      rowbeg = (int*)ws;      ws += (size_t)N_NODES * 4;             // 0.4MB
    int*      rowend = (int*)ws;      ws += (size_t)N_NODES * 4;             // 0.4MB
    int*      bcnt   = (int*)ws;      ws += NBUCK * 4;
    int*      bbase  = (int*)ws;      ws += NBUCK * 4;
    float*    Wf     = (float*)ws;    ws += H1 * C_OUT * 4;
    float*    bhead  = (float*)ws;    ws += C_OUT * 4;

    // ---- coarse bin (single pass) + xb compression, fused
    hipMemsetAsync(bcnt, 0, NBUCK * 4, stream);
    binA_xb_k<<<NBLK_A + XB_BLOCKS, 256, 0, stream>>>(
        esrc, edst, ew, bcnt, binned, x, xb);

    // ---- bucket-base scan (8-rounded regions) + head weight fold, fused
    scanB_wf_k<<<2, 512, 0, stream>>>(bcnt, bbase, W2, Wm, b2, bm, Wf, bhead);

    // ---- fine sort (writes rowbeg/rowend + padded rec_s)
    binB_k<<<NBUCK, 512, 0, stream>>>(binned, bcnt, bbase, rowbeg, rowend, rec_s);

    // ---- layer 1 fused through z = h1@Wf; layer 2 + head
    layer1z_k<<<N_NODES / 8, 256, 0, stream>>>(xb, rowbeg, rowend, rec_s, W1, b1, Wf, z);
    agg4_k<<<N_NODES / 32, 256, 0, stream>>>(z, rowbeg, rowend, rec_s, bhead, out);
}

// Round 17
// 109.744 us; speedup vs baseline: 1.4491x; 1.0540x over previous
//
#include <hip/hip_runtime.h>

#define N_NODES 100000
#define N_EDGES 1600000
#define F_IN 22
#define H1 128
#define H2 256
#define C_OUT 4

// Edge record: 4 bytes. src in bits [31:15] (17 bits); bits [14:0] hold the
// bf16 bit-pattern of w (RNE). For w in [0,1], bf16 bits <= 0x3F80 < 2^15.
#define WDEC(q) __uint_as_float(((q) & 0x7fffu) << 16)
#define BFLO(u) __uint_as_float((u) << 16)
#define BFHI(u) __uint_as_float((u) & 0xFFFF0000u)

// Two-level binned sort parameters
#define BSHIFT 9                  // 512 nodes per bucket
#define NBUCK 196                 // ceil(100000/512)
#define CHUNK 4096                // edges per binA block (LDS-staged)
#define NBLK_A 391                // ceil(1.6M/4096)
#define BCAP 12288                // bucket capacity (padded totals <= ~12.2K)
#define BSLACK 3584               // 512 nodes * 7 max pad per node
#define XB_BLOCKS 4297            // ceil(100000*11/256)

typedef __attribute__((ext_vector_type(8))) short bf16x8;
typedef __attribute__((ext_vector_type(4))) float f32x4;

// ---------------------------------------------------------------------------
// binA_xb_k: FUSED. Blocks [0,NBLK_A): single-pass coarse bin. Blocks
// [NBLK_A,...): xb compression (x -> packed bf16 pairs).
// ---------------------------------------------------------------------------
__global__ __launch_bounds__(256) void binA_xb_k(
    const int* __restrict__ esrc, const int* __restrict__ edst,
    const float* __restrict__ ew, int* __restrict__ bcnt,
    uint2* __restrict__ binned,
    const float* __restrict__ x, unsigned* __restrict__ xb)
{
    __shared__ uint2 l_rec[CHUNK];          // 32KB
    __shared__ int l_base[NBUCK];
    __shared__ int l_cnt[NBUCK];
    int t = threadIdx.x;
    int bid = blockIdx.x;

    if (bid >= NBLK_A) {
        int i = (bid - NBLK_A) * 256 + t;
        if (i < N_NODES * 11) {
            int n = i / 11, p = i - n * 11;
            unsigned u0 = __float_as_uint(x[n * F_IN + 2 * p]);
            unsigned u1 = __float_as_uint(x[n * F_IN + 2 * p + 1]);
            u0 = (u0 + 0x7fffu + ((u0 >> 16) & 1u)) >> 16;
            u1 = (u1 + 0x7fffu + ((u1 >> 16) & 1u)) >> 16;
            xb[i] = u0 | (u1 << 16);
        }
        return;
    }

    int e0 = bid * CHUNK;
    int n = min(CHUNK, N_EDGES - e0);

    for (int i = t; i < NBUCK; i += 256) l_cnt[i] = 0;
    __syncthreads();
    for (int i = t; i < n; i += 256) {
        int e = e0 + i;
        int d = edst[e];
        unsigned u = __float_as_uint(ew[e]);
        unsigned bw = (u + 0x7fffu + ((u >> 16) & 1u)) >> 16;
        unsigned rec = ((unsigned)esrc[e] << 15) | bw;
        l_rec[i] = make_uint2(rec, (unsigned)d);
        atomicAdd(&l_cnt[d >> BSHIFT], 1);
    }
    __syncthreads();
    for (int i = t; i < NBUCK; i += 256) {
        int c = l_cnt[i];
        l_base[i] = c ? atomicAdd(&bcnt[i], c) : 0;
    }
    __syncthreads();
    for (int i = t; i < NBUCK; i += 256) l_cnt[i] = 0;
    __syncthreads();
    for (int i = t; i < n; i += 256) {
        uint2 r = l_rec[i];
        int d = (int)r.y;
        int b = d >> BSHIFT;
        int off = l_base[b] + atomicAdd(&l_cnt[b], 1);
        if (off < BCAP)
            binned[(size_t)b * BCAP + off] = make_uint2(r.x, (unsigned)(d & 511));
    }
}

// ---------------------------------------------------------------------------
// scanB_wf_k: block 0: exclusive scan of 8-rounded bucket regions -> bbase.
// Block 1: Wf = W2@Wm, bhead = b2@Wm + bm.
// ---------------------------------------------------------------------------
__global__ __launch_bounds__(512) void scanB_wf_k(
    const int* __restrict__ bcnt, int* __restrict__ bbase,
    const float* __restrict__ W2, const float* __restrict__ Wm,
    const float* __restrict__ b2, const float* __restrict__ bm,
    float* __restrict__ Wf, float* __restrict__ bhead)
{
    int t = threadIdx.x;
    if (blockIdx.x == 0) {
        __shared__ int sA[512], sB[512];
        int v = (t < NBUCK) ? ((bcnt[t] + BSLACK + 7) & ~7) : 0;
        sA[t] = v; __syncthreads();
        int* src = sA; int* dst = sB;
        for (int off = 1; off < 512; off <<= 1) {
            dst[t] = src[t] + (t >= off ? src[t - off] : 0);
            __syncthreads();
            int* tmp = src; src = dst; dst = tmp;
        }
        if (t < NBUCK) bbase[t] = (t > 0) ? src[t - 1] : 0;
    } else {
        int k = t >> 2, c = t & 3;
        float acc = 0.f;
        for (int j = 0; j < H2; ++j)
            acc = fmaf(W2[k * H2 + j], Wm[j * C_OUT + c], acc);
        Wf[k * C_OUT + c] = acc;
        if (t < C_OUT) {
            float a = bm[t];
            for (int j = 0; j < H2; ++j)
                a = fmaf(b2[j], Wm[j * C_OUT + t], a);
            bhead[t] = a;
        }
    }
}

// ---------------------------------------------------------------------------
// binB_k: one block per bucket. Per-node histogram -> PADDED (multiple of 8)
// exclusive scan -> rowbeg/rowend -> LDS-scatter (zero-filled pad) ->
// coalesced write. Pad records are 0 (src=0, w=0): contribute exactly 0.
// ---------------------------------------------------------------------------
__global__ __launch_bounds__(512) void binB_k(
    const uint2* __restrict__ binned, const int* __restrict__ bcnt,
    const int* __restrict__ bbase, int* __restrict__ rowbeg,
    int* __restrict__ rowend, unsigned* __restrict__ rec_s)
{
    __shared__ int l_hist[512];
    __shared__ int sA[512], sB[512];
    __shared__ int l_cur[512];
    __shared__ unsigned l_out[BCAP];
    int b = blockIdx.x;
    int t = threadIdx.x;
    int node0 = b << BSHIFT;
    int base = bbase[b];
    int cnt = min(bcnt[b], BCAP);
    const uint2* reg = binned + (size_t)b * BCAP;

    l_hist[t] = 0;
    __syncthreads();
    for (int i = t; i < cnt; i += 512)
        atomicAdd(&l_hist[reg[i].y], 1);
    __syncthreads();
    int pc = (l_hist[t] + 7) & ~7;
    sA[t] = pc; __syncthreads();
    int* src = sA; int* dst = sB;
    for (int off = 1; off < 512; off <<= 1) {
        dst[t] = src[t] + (t >= off ? src[t - off] : 0);
        __syncthreads();
        int* tmp = src; src = dst; dst = tmp;
    }
    int excl = (t > 0) ? src[t - 1] : 0;
    int ptot = src[511];
    int node = node0 + t;
    if (node < N_NODES) {
        rowbeg[node] = base + excl;
        rowend[node] = base + excl + pc;
    }
    l_cur[t] = excl;
    __syncthreads();
    for (int i = t; i < ptot; i += 512) l_out[i] = 0;
    __syncthreads();
    for (int i = t; i < cnt; i += 512) {
        uint2 r = reg[i];
        int p = atomicAdd(&l_cur[r.y], 1);
        l_out[p] = r.x;
    }
    __syncthreads();
    for (int i = t; i < ptot; i += 512)
        rec_s[base + i] = l_out[i];
}

// ---------------------------------------------------------------------------
// agg1_k: y[d] = sum_e w_e * x[src_e]  (aggregation ONLY — round-16 edge
// loop, epilogue removed). Output yb: packed bf16 rows of 32 (k 22..31 = 0),
// ready to be MFMA A-fragments. No LDS, low VGPR.
// ---------------------------------------------------------------------------
__global__ __launch_bounds__(256) void agg1_k(
    const unsigned* __restrict__ xb,
    const int* __restrict__ rowbeg,
    const int* __restrict__ rowend,
    const unsigned* __restrict__ rec,
    unsigned* __restrict__ yb)
{
    int tid = threadIdx.x;
    int g = tid >> 5, lane = tid & 31;
    int d = blockIdx.x * 8 + g;
    int beg = rowbeg[d], end = rowend[d];   // end-beg is a multiple of 8

    int l2 = lane < 22 ? lane : 21;
    int eslot = l2 >= 11;
    int pair = l2 - 11 * eslot;

    float aA0 = 0.f, aA1 = 0.f, aA2 = 0.f, aA3 = 0.f;
    float aB0 = 0.f, aB1 = 0.f, aB2 = 0.f, aB3 = 0.f;
    int j = beg;
    for (; j + 16 <= end; j += 16) {
        const uint4* r4 = (const uint4*)(rec + j + 8 * eslot);
        uint4 qa = r4[0];
        uint4 qb = r4[1];
        unsigned x0 = xb[(size_t)(qa.x >> 15) * 11 + pair];
        unsigned x1 = xb[(size_t)(qa.y >> 15) * 11 + pair];
        unsigned x2 = xb[(size_t)(qa.z >> 15) * 11 + pair];
        unsigned x3 = xb[(size_t)(qa.w >> 15) * 11 + pair];
        unsigned x4 = xb[(size_t)(qb.x >> 15) * 11 + pair];
        unsigned x5 = xb[(size_t)(qb.y >> 15) * 11 + pair];
        unsigned x6 = xb[(size_t)(qb.z >> 15) * 11 + pair];
        unsigned x7 = xb[(size_t)(qb.w >> 15) * 11 + pair];
        float w0 = WDEC(qa.x), w1 = WDEC(qa.y), w2 = WDEC(qa.z), w3 = WDEC(qa.w);
        float w4 = WDEC(qb.x), w5 = WDEC(qb.y), w6 = WDEC(qb.z), w7 = WDEC(qb.w);
        aA0 = fmaf(w0, BFLO(x0), aA0); aB0 = fmaf(w0, BFHI(x0), aB0);
        aA1 = fmaf(w1, BFLO(x1), aA1); aB1 = fmaf(w1, BFHI(x1), aB1);
        aA2 = fmaf(w2, BFLO(x2), aA2); aB2 = fmaf(w2, BFHI(x2), aB2);
        aA3 = fmaf(w3, BFLO(x3), aA3); aB3 = fmaf(w3, BFHI(x3), aB3);
        aA0 = fmaf(w4, BFLO(x4), aA0); aB0 = fmaf(w4, BFHI(x4), aB0);
        aA1 = fmaf(w5, BFLO(x5), aA1); aB1 = fmaf(w5, BFHI(x5), aB1);
        aA2 = fmaf(w6, BFLO(x6), aA2); aB2 = fmaf(w6, BFHI(x6), aB2);
        aA3 = fmaf(w7, BFLO(x7), aA3); aB3 = fmaf(w7, BFHI(x7), aB3);
    }
    if (j < end) {
        const uint4* r4 = (const uint4*)(rec + j + 4 * eslot);
        uint4 q = r4[0];
        unsigned x0 = xb[(size_t)(q.x >> 15) * 11 + pair];
        unsigned x1 = xb[(size_t)(q.y >> 15) * 11 + pair];
        unsigned x2 = xb[(size_t)(q.z >> 15) * 11 + pair];
        unsigned x3 = xb[(size_t)(q.w >> 15) * 11 + pair];
        float w0 = WDEC(q.x), w1 = WDEC(q.y), w2 = WDEC(q.z), w3 = WDEC(q.w);
        aA0 = fmaf(w0, BFLO(x0), aA0); aB0 = fmaf(w0, BFHI(x0), aB0);
        aA1 = fmaf(w1, BFLO(x1), aA1); aB1 = fmaf(w1, BFHI(x1), aB1);
        aA2 = fmaf(w2, BFLO(x2), aA2); aB2 = fmaf(w2, BFHI(x2), aB2);
        aA3 = fmaf(w3, BFLO(x3), aA3); aB3 = fmaf(w3, BFHI(x3), aB3);
    }
    float sA = (aA0 + aA1) + (aA2 + aA3);
    float sB = (aB0 + aB1) + (aB2 + aB3);
    float oA = __shfl(sA, 11 + pair, 32);
    float oB = __shfl(sB, 11 + pair, 32);
    // lanes 0..10 hold features 2p (sA+oA) and 2p+1 (sB+oB); pack bf16 RNE
    unsigned u = 0;
    if (lane < 11) {
        unsigned ua = __float_as_uint(sA + oA);
        ua = (ua + 0x7fffu + ((ua >> 16) & 1u)) >> 16;
        unsigned ub = __float_as_uint(sB + oB);
        ub = (ub + 0x7fffu + ((ub >> 16) & 1u)) >> 16;
        u = ua | (ub << 16);
    }
    if (lane < 16)
        yb[(size_t)d * 16 + lane] = u;   // k 22..31 zeroed (lanes 11..15)
}

// ---------------------------------------------------------------------------
// gemmz_k: z = (relu(Y @ W1 + b1)) @ Wf via MFMA. Per 64-node block, 4 waves;
// wave handles 16 nodes x 128 cols with 8x mfma_f32_16x16x32_bf16.
// A frag: lane l holds Y[node0 + (l&15)][k = 8*(l>>4)+i] (one uint4 load).
// B frag (LDS-staged): lane l holds W1[8*(l>>4)+i][16b + (l&15)] as bf16.
// C layout (verified): lane l holds C[4*(l>>4)+i][16b + (l&15)].
// bias+relu on C frags, Wf fold in registers, 16-lane shfl reduce -> z.
// ---------------------------------------------------------------------------
__global__ __launch_bounds__(256) void gemmz_k(
    const unsigned* __restrict__ yb,
    const float* __restrict__ W1,
    const float* __restrict__ b1,
    const float* __restrict__ Wf,
    float4* __restrict__ z)
{
    __shared__ short w1b[8][64][8];   // 8KB: B frags per 16-col block
    __shared__ float4 wsf4[H1];       // 2KB
    __shared__ float bs[H1];          // 0.5KB
    int tid = threadIdx.x;

    for (int idx = tid; idx < 8 * 64 * 8; idx += 256) {
        int b = idx >> 9;
        int r = idx & 511;
        int l = r >> 3, i = r & 7;
        int k = 8 * (l >> 4) + i;
        int col = 16 * b + (l & 15);
        float v = (k < F_IN) ? W1[k * H1 + col] : 0.f;
        unsigned u = __float_as_uint(v);
        u = (u + 0x7fffu + ((u >> 16) & 1u)) >> 16;
        w1b[b][l][i] = (short)u;
    }
    if (tid < H1) { wsf4[tid] = ((const float4*)Wf)[tid]; bs[tid] = b1[tid]; }
    __syncthreads();

    int wid = tid >> 6, lane = tid & 63;
    int node0 = blockIdx.x * 64 + wid * 16;
    if (node0 >= N_NODES) return;
    int row = lane & 15, q = lane >> 4;

    uint4 av = ((const uint4*)yb)[(size_t)(node0 + row) * 4 + q];
    bf16x8 af = *(bf16x8*)&av;

    float zp[4][4];
#pragma unroll
    for (int i = 0; i < 4; ++i)
#pragma unroll
        for (int c = 0; c < 4; ++c) zp[i][c] = 0.f;

#pragma unroll
    for (int b = 0; b < 8; ++b) {
        bf16x8 bf = *(bf16x8*)&w1b[b][lane][0];
        f32x4 c = __builtin_amdgcn_mfma_f32_16x16x32_bf16(
            af, bf, (f32x4){0.f, 0.f, 0.f, 0.f}, 0, 0, 0);
        int col = 16 * b + (lane & 15);
        float bias = bs[col];
        float4 wv = wsf4[col];
#pragma unroll
        for (int i = 0; i < 4; ++i) {
            float v = c[i] + bias;
            v = v > 0.f ? v : 0.f;
            zp[i][0] = fmaf(v, wv.x, zp[i][0]);
            zp[i][1] = fmaf(v, wv.y, zp[i][1]);
            zp[i][2] = fmaf(v, wv.z, zp[i][2]);
            zp[i][3] = fmaf(v, wv.w, zp[i][3]);
        }
    }
    // reduce over the 16 cols-lanes; xor masks 1..8 stay within the group
#pragma unroll
    for (int mask = 8; mask >= 1; mask >>= 1)
#pragma unroll
        for (int i = 0; i < 4; ++i) {
            zp[i][0] += __shfl_xor(zp[i][0], mask, 64);
            zp[i][1] += __shfl_xor(zp[i][1], mask, 64);
            zp[i][2] += __shfl_xor(zp[i][2], mask, 64);
            zp[i][3] += __shfl_xor(zp[i][3], mask, 64);
        }
    if ((lane & 15) == 0) {
#pragma unroll
        for (int i = 0; i < 4; ++i) {
            int n = node0 + 4 * q + i;
            z[n] = make_float4(zp[i][0], zp[i][1], zp[i][2], zp[i][3]);
        }
    }
}

// ---------------------------------------------------------------------------
// agg4_k: out[d] = log_softmax( (sum_e w_e * z[src_e]) + bhead ).
// ---------------------------------------------------------------------------
__global__ __launch_bounds__(256) void agg4_k(
    const float4* __restrict__ z,
    const int* __restrict__ rowbeg,
    const int* __restrict__ rowend,
    const unsigned* __restrict__ rec,
    const float* __restrict__ bhead,
    float* __restrict__ out)
{
    int tid = threadIdx.x;
    int g = tid >> 3, sub = tid & 7;
    int d = blockIdx.x * 32 + g;
    int beg = rowbeg[d], end = rowend[d];

    float4 acc = {0.f, 0.f, 0.f, 0.f};
    for (int j = beg + sub; j < end; j += 8) {
        unsigned r = rec[j];
        float w = WDEC(r);
        float4 v = z[r >> 15];
        acc.x = fmaf(w, v.x, acc.x);
        acc.y = fmaf(w, v.y, acc.y);
        acc.z = fmaf(w, v.z, acc.z);
        acc.w = fmaf(w, v.w, acc.w);
    }
#pragma unroll
    for (int mask = 4; mask >= 1; mask >>= 1) {
        acc.x += __shfl_xor(acc.x, mask, 64);
        acc.y += __shfl_xor(acc.y, mask, 64);
        acc.z += __shfl_xor(acc.z, mask, 64);
        acc.w += __shfl_xor(acc.w, mask, 64);
    }
    if (sub == 0) {
        float l0 = acc.x + bhead[0];
        float l1 = acc.y + bhead[1];
        float l2 = acc.z + bhead[2];
        float l3 = acc.w + bhead[3];
        float mx = fmaxf(fmaxf(l0, l1), fmaxf(l2, l3));
        float s = expf(l0 - mx) + expf(l1 - mx) + expf(l2 - mx) + expf(l3 - mx);
        float lg = mx + logf(s);
        ((float4*)out)[d] = make_float4(l0 - lg, l1 - lg, l2 - lg, l3 - lg);
    }
}

extern "C" void kernel_launch(void* const* d_in, const int* in_sizes, int n_in,
                              void* d_out, int out_size, void* d_ws, size_t ws_size,
                              hipStream_t stream) {
    const float* x    = (const float*)d_in[0];
    const int*   esrc = (const int*)d_in[1];
    const int*   edst = (const int*)d_in[2];
    const float* ew   = (const float*)d_in[3];
    const float* W1   = (const float*)d_in[4];
    const float* b1   = (const float*)d_in[5];
    const float* W2   = (const float*)d_in[6];
    const float* b2   = (const float*)d_in[7];
    const float* Wm   = (const float*)d_in[8];
    const float* bm   = (const float*)d_in[9];
    float* out = (float*)d_out;

    // workspace layout (~43 MB)
    char* ws = (char*)d_ws;
    float4*   z      = (float4*)ws;   ws += (size_t)N_NODES * 16;            // 1.6MB
    uint2*    binned = (uint2*)ws;    ws += (size_t)NBUCK * BCAP * 8;        // 19.3MB
    unsigned* rec_s  = (unsigned*)ws; ws += (size_t)(N_EDGES + NBUCK * (BSLACK + 8)) * 4;
    unsigned* xb     = (unsigned*)ws; ws += (size_t)N_NODES * 11 * 4;        // 4.4MB
    unsigned* yb     = (unsigned*)ws; ws += (size_t)N_NODES * 16 * 4;        // 6.4MB
    int*      rowbeg = (int*)ws;      ws += (size_t)N_NODES * 4;             // 0.4MB
    int*      rowend = (int*)ws;      ws += (size_t)N_NODES * 4;             // 0.4MB
    int*      bcnt   = (int*)ws;      ws += NBUCK * 4;
    int*      bbase  = (int*)ws;      ws += NBUCK * 4;
    float*    Wf     = (float*)ws;    ws += H1 * C_OUT * 4;
    float*    bhead  = (float*)ws;    ws += C_OUT * 4;

    // ---- coarse bin (single pass) + xb compression, fused
    hipMemsetAsync(bcnt, 0, NBUCK * 4, stream);
    binA_xb_k<<<NBLK_A + XB_BLOCKS, 256, 0, stream>>>(
        esrc, edst, ew, bcnt, binned, x, xb);

    // ---- bucket-base scan + head weight fold, fused
    scanB_wf_k<<<2, 512, 0, stream>>>(bcnt, bbase, W2, Wm, b2, bm, Wf, bhead);

    // ---- fine sort (writes rowbeg/rowend + padded rec_s)
    binB_k<<<NBUCK, 512, 0, stream>>>(binned, bcnt, bbase, rowbeg, rowend, rec_s);

    // ---- layer 1: aggregation (VALU) then dense via MFMA
    agg1_k<<<N_NODES / 8, 256, 0, stream>>>(xb, rowbeg, rowend, rec_s, yb);
    gemmz_k<<<(N_NODES + 63) / 64, 256, 0, stream>>>(yb, W1, b1, Wf, z);

    // ---- layer 2 + head
    agg4_k<<<N_NODES / 32, 256, 0, stream>>>(z, rowbeg, rowend, rec_s, bhead, out);
}